// Round 3
// baseline (649.129 us; speedup 1.0000x reference)
//
#include <hip/hip_runtime.h>
#include <math.h>

#define NN 8192
#define KDIM 256
#define DD 64
#define NB 4096
#define NBLK 256
#define NTHR 512
#define RPB 32           // rows per block
#define CH 32            // sorted elements per chunk
#define NCH 256          // chunks
#define LRALPHA 0.2f

__device__ __forceinline__ unsigned f2k(float f) {
    unsigned u = __float_as_uint(f);
    return u ^ ((u >> 31) ? 0xFFFFFFFFu : 0x80000000u);
}
__device__ __forceinline__ float k2f(unsigned k) {
    return __uint_as_float((k & 0x80000000u) ? (k ^ 0x80000000u) : ~k);
}
// monotone non-decreasing key->bucket map (same formula everywhere)
__device__ __forceinline__ unsigned bucket_of(unsigned key, unsigned kmin, float scale) {
    unsigned d = key - kmin;
    unsigned b = (unsigned)((float)d * scale);
    return b > (NB - 1) ? (NB - 1) : b;
}

// monotone-counter grid barrier: co-residency guaranteed (256 blocks, ~21KB LDS, VGPR<=256)
__device__ __forceinline__ void gridbar(int* cnt, int target) {
    __threadfence();
    __syncthreads();
    if (threadIdx.x == 0) {
        __hip_atomic_fetch_add(cnt, 1, __ATOMIC_ACQ_REL, __HIP_MEMORY_SCOPE_AGENT);
        while (__hip_atomic_load(cnt, __ATOMIC_ACQUIRE, __HIP_MEMORY_SCOPE_AGENT) < target)
            __builtin_amdgcn_s_sleep(2);
    }
    __syncthreads();
    __threadfence();
}

__global__ __launch_bounds__(NTHR, 2) void k_fused(
    const float* __restrict__ h, const float* __restrict__ W,
    const float* __restrict__ a, float* __restrict__ out,
    float* Wh, float* Wh2g, float* sv, float* wnv, float* wpv,
    float* cs_neg, float* cs_pos, float* cs_sn, float* cs_sp,
    float* PN, float* SP, float* PNs, float* SPs,
    int* sidx, int* histcur, int* barcnt)
{
    __shared__ int      ls_bstart[NB + 1];     // 16.4 KB (hist -> scanned in place, persists to S5)
    __shared__ float    ls_wh1[RPB];
    __shared__ float    ls_wh2[RPB];
    __shared__ unsigned ls_ra[8], ls_rb[8];
    __shared__ int      ls_wsum[8];
    __shared__ float    ls_cs[8][2 * DD];      // 4 KB scratch (S3 / S4)
    __shared__ float    ls_css[16];
    __shared__ float    ls_M2, ls_scale;
    __shared__ unsigned ls_kmin;

    const int t = threadIdx.x, bid = blockIdx.x;
    const int wv = t >> 6, lane = t & 63;
    const int rowBase = bid * RPB;

    // ================= S0: GEMM (4 rows per wave) =================
    {
        const int r0 = rowBase + wv * 4;
        float acc0 = 0.f, acc1 = 0.f, acc2 = 0.f, acc3 = 0.f;
        #pragma unroll 2
        for (int k4 = 0; k4 < KDIM / 4; ++k4) {
            float w0 = W[(4 * k4 + 0) * DD + lane];
            float w1 = W[(4 * k4 + 1) * DD + lane];
            float w2 = W[(4 * k4 + 2) * DD + lane];
            float w3 = W[(4 * k4 + 3) * DD + lane];
            float4 h0 = *(const float4*)(h + (size_t)(r0 + 0) * KDIM + 4 * k4);
            float4 h1 = *(const float4*)(h + (size_t)(r0 + 1) * KDIM + 4 * k4);
            float4 h2 = *(const float4*)(h + (size_t)(r0 + 2) * KDIM + 4 * k4);
            float4 h3 = *(const float4*)(h + (size_t)(r0 + 3) * KDIM + 4 * k4);
            acc0 = fmaf(h0.x, w0, acc0); acc0 = fmaf(h0.y, w1, acc0);
            acc0 = fmaf(h0.z, w2, acc0); acc0 = fmaf(h0.w, w3, acc0);
            acc1 = fmaf(h1.x, w0, acc1); acc1 = fmaf(h1.y, w1, acc1);
            acc1 = fmaf(h1.z, w2, acc1); acc1 = fmaf(h1.w, w3, acc1);
            acc2 = fmaf(h2.x, w0, acc2); acc2 = fmaf(h2.y, w1, acc2);
            acc2 = fmaf(h2.z, w2, acc2); acc2 = fmaf(h2.w, w3, acc2);
            acc3 = fmaf(h3.x, w0, acc3); acc3 = fmaf(h3.y, w1, acc3);
            acc3 = fmaf(h3.z, w2, acc3); acc3 = fmaf(h3.w, w3, acc3);
        }
        float a1 = a[lane], a2 = a[DD + lane];
        float accs[4] = {acc0, acc1, acc2, acc3};
        #pragma unroll
        for (int i = 0; i < 4; ++i) {
            int row = r0 + i;
            Wh[(size_t)row * DD + lane] = accs[i];
            float r1 = accs[i] * a1, r2 = accs[i] * a2;
            #pragma unroll
            for (int off = 32; off > 0; off >>= 1) {
                r1 += __shfl_xor(r1, off, 64);
                r2 += __shfl_xor(r2, off, 64);
            }
            if (lane == 0) {
                Wh2g[row] = r2;
                ls_wh1[wv * 4 + i] = r1;
                ls_wh2[wv * 4 + i] = r2;
            }
        }
    }
    gridbar(barcnt, NBLK * 1);

    // ================= S1: redundant min/max + hist + scan -> LDS bstart =================
    for (int i = t; i < NB; i += NTHR) ls_bstart[i] = 0;
    {
        unsigned lmin = 0xFFFFFFFFu, lmax = 0u;
        for (int i = t; i < NN; i += NTHR) {
            unsigned k = f2k(Wh2g[i]);
            lmin = min(lmin, k); lmax = max(lmax, k);
        }
        #pragma unroll
        for (int off = 32; off > 0; off >>= 1) {
            lmin = min(lmin, (unsigned)__shfl_xor((int)lmin, off, 64));
            lmax = max(lmax, (unsigned)__shfl_xor((int)lmax, off, 64));
        }
        if (lane == 0) { ls_ra[wv] = lmin; ls_rb[wv] = lmax; }
    }
    __syncthreads();
    if (t == 0) {
        unsigned mn = ls_ra[0], mx = ls_rb[0];
        for (int i = 1; i < 8; ++i) { mn = min(mn, ls_ra[i]); mx = max(mx, ls_rb[i]); }
        ls_kmin = mn;
        ls_scale = (float)NB / ((float)(mx - mn) + 1.0f);
        ls_M2 = k2f(mx);
    }
    __syncthreads();
    const unsigned kmin = ls_kmin;
    const float scale = ls_scale;
    const float M2 = ls_M2;

    for (int i = t; i < NN; i += NTHR)
        atomicAdd(&ls_bstart[bucket_of(f2k(Wh2g[i]), kmin, scale)], 1);
    __syncthreads();
    {
        int s[8]; int tot = 0;
        #pragma unroll
        for (int j = 0; j < 8; ++j) { s[j] = ls_bstart[8 * t + j]; tot += s[j]; }
        int x = tot;
        #pragma unroll
        for (int off = 1; off < 64; off <<= 1) {
            int y = __shfl_up(x, off, 64);
            if (lane >= off) x += y;
        }
        if (lane == 63) ls_wsum[wv] = x;
        __syncthreads();
        int woff = 0;
        for (int w2 = 0; w2 < wv; ++w2) woff += ls_wsum[w2];
        int acc = woff + x - tot;
        #pragma unroll
        for (int j = 0; j < 8; ++j) { ls_bstart[8 * t + j] = acc; acc += s[j]; }
        if (t == 0) ls_bstart[NB] = NN;
    }
    __syncthreads();
    // one writer per bin range: block bid owns [16*bid, 16*bid+16)
    if (t < 16) histcur[16 * bid + t] = ls_bstart[16 * bid + t];

    gridbar(barcnt, NBLK * 2);

    // ================= S2: scatter own 32 elements =================
    if (t < RPB) {
        float x = ls_wh2[t];
        unsigned b = bucket_of(f2k(x), kmin, scale);
        int pos = atomicAdd(&histcur[b], 1);
        sv[pos] = x;
        sidx[pos] = rowBase + t;
        wnv[pos] = expf(LRALPHA * (x - M2));   // <= 1
        wpv[pos] = expf(x - M2);               // <= 1
    }
    gridbar(barcnt, NBLK * 3);

    // ================= S3: chunk sums (chunk = bid) =================
    {
        int base = bid * CH + wv * 4;
        float an = 0.f, ap = 0.f, sn = 0.f, sp = 0.f;
        #pragma unroll
        for (int kk = 0; kk < 4; ++kk) {
            int k = base + kk;
            int j = sidx[k];
            float g = Wh[(size_t)j * DD + lane];
            float wnk = wnv[k], wpk = wpv[k];
            an = fmaf(wnk, g, an); ap = fmaf(wpk, g, ap);
            sn += wnk; sp += wpk;
        }
        ls_cs[wv][lane] = an; ls_cs[wv][DD + lane] = ap;
        if (lane == 0) { ls_css[wv] = sn; ls_css[8 + wv] = sp; }
        __syncthreads();
        if (wv == 0) {
            float s = 0.f;
            #pragma unroll
            for (int w2 = 0; w2 < 8; ++w2) s += ls_cs[w2][lane];
            cs_neg[bid * DD + lane] = s;
            if (lane == 0) { float ss = 0.f; for (int w2 = 0; w2 < 8; ++w2) ss += ls_css[w2]; cs_sn[bid] = ss; }
        } else if (wv == 1) {
            float s = 0.f;
            #pragma unroll
            for (int w2 = 0; w2 < 8; ++w2) s += ls_cs[w2][DD + lane];
            cs_pos[bid * DD + lane] = s;
            if (lane == 0) { float ss = 0.f; for (int w2 = 0; w2 < 8; ++w2) ss += ls_css[8 + w2]; cs_sp[bid] = ss; }
        }
    }
    gridbar(barcnt, NBLK * 4);

    // ================= S4: block 0 scans the 256 chunks =================
    if (bid == 0) {
        const int c0 = wv * 32;
        float ln = 0.f, lp = 0.f, lsn = 0.f, lsp = 0.f;
        for (int c = c0; c < c0 + 32; ++c) {
            ln += cs_neg[c * DD + lane];
            lp += cs_pos[c * DD + lane];
            lsn += cs_sn[c];
            lsp += cs_sp[c];
        }
        ls_cs[wv][lane] = ln; ls_cs[wv][DD + lane] = lp;
        if (lane == 0) { ls_css[wv] = lsn; ls_css[8 + wv] = lsp; }
        __syncthreads();
        float offN = 0.f, offP = 0.f, offNs = 0.f, offPs = 0.f;
        for (int w2 = 0; w2 < wv; ++w2) { offN += ls_cs[w2][lane]; offNs += ls_css[w2]; }
        for (int w2 = wv + 1; w2 < 8; ++w2) { offP += ls_cs[w2][DD + lane]; offPs += ls_css[8 + w2]; }
        float accn = offN, accns = offNs;
        for (int c = c0; c < c0 + 32; ++c) {
            PN[c * DD + lane] = accn;
            if (lane == 0) PNs[c] = accns;
            accn += cs_neg[c * DD + lane];
            accns += cs_sn[c];
        }
        if (wv == 7) {
            PN[NCH * DD + lane] = accn;
            SP[NCH * DD + lane] = 0.f;
            if (lane == 0) { PNs[NCH] = accns; SPs[NCH] = 0.f; }
        }
        float accp = offP, accps = offPs;
        for (int c = c0 + 31; c >= c0; --c) {
            accp += cs_pos[c * DD + lane];
            accps += cs_sp[c];
            SP[c * DD + lane] = accp;
            if (lane == 0) SPs[c] = accps;
        }
    }
    gridbar(barcnt, NBLK * 5);

    // ================= S5: output (4 rows per wave) =================
    for (int i = 0; i < 4; ++i) {
        int lr = wv * 4 + i;
        int row = rowBase + lr;
        float w1 = ls_wh1[lr];
        float z = w1 + M2;                          // max_j (Wh1_i + Wh2_j)
        float m = (z >= 0.f) ? z : LRALPHA * z;     // lrelu(z) = exact row max
        float c1 = expf(z - m);                     // exponent <= 0
        float c2 = expf(LRALPHA * z - m);           // exponent <= 0
        float tt = -w1;
        unsigned kt = f2k(tt);
        int p0 = 0, p1 = 0;
        if (kt >= kmin) {
            unsigned b = bucket_of(kt, kmin, scale);
            p0 = ls_bstart[b]; p1 = ls_bstart[b + 1];
        }
        int c0f = p0 >> 5;            // CH = 32
        int c1e = (p1 + 31) >> 5;
        float nn_ = PN[c0f * DD + lane], dn_ = PNs[c0f];
        float np_ = SP[c1e * DD + lane], dp_ = SPs[c1e];
        for (int k = c0f * 32; k < c1e * 32; ++k) {
            float vk = sv[k];
            int j = sidx[k];
            float g = Wh[(size_t)j * DD + lane];
            if (vk <= tt) { float wk = wnv[k]; nn_ = fmaf(wk, g, nn_); dn_ += wk; }
            else          { float wk = wpv[k]; np_ = fmaf(wk, g, np_); dp_ += wk; }
        }
        float num = c2 * nn_ + c1 * np_;
        float den = c2 * dn_ + c1 * dp_;
        float r = num / den;
        out[(size_t)row * DD + lane] = (r > 0.f) ? r : expm1f(r);   // elu
    }
}

extern "C" void kernel_launch(void* const* d_in, const int* in_sizes, int n_in,
                              void* d_out, int out_size, void* d_ws, size_t ws_size,
                              hipStream_t stream)
{
    const float* h = (const float*)d_in[0];
    // d_in[1] = adj (bool, unused by the reference computation)
    const float* W = (const float*)d_in[2];
    const float* a = (const float*)d_in[3];
    float* out = (float*)d_out;
    float* ws = (float*)d_ws;

    float* Wh     = ws;                              // NN*DD
    float* Wh2g   = Wh + (size_t)NN * DD;            // NN
    float* sv     = Wh2g + NN;                       // NN
    float* wnv    = sv + NN;                         // NN
    float* wpv    = wnv + NN;                        // NN
    float* cs_neg = wpv + NN;                        // NCH*DD
    float* cs_pos = cs_neg + NCH * DD;               // NCH*DD
    float* cs_sn  = cs_pos + NCH * DD;               // NCH
    float* cs_sp  = cs_sn + NCH;                     // NCH
    float* PN     = cs_sp + NCH;                     // (NCH+1)*DD
    float* SP     = PN + (NCH + 1) * DD;             // (NCH+1)*DD
    float* PNs    = SP + (NCH + 1) * DD;             // NCH+1
    float* SPs    = PNs + (NCH + 1);                 // NCH+1
    int*   sidx   = (int*)(SPs + (NCH + 1));         // NN
    int*   histcur= sidx + NN;                       // NB
    int*   barcnt = histcur + NB;                    // few

    hipMemsetAsync(barcnt, 0, 256, stream);
    k_fused<<<NBLK, NTHR, 0, stream>>>(h, W, a, out,
        Wh, Wh2g, sv, wnv, wpv,
        cs_neg, cs_pos, cs_sn, cs_sp,
        PN, SP, PNs, SPs,
        sidx, histcur, barcnt);
}

// Round 4
// 502.456 us; speedup vs baseline: 1.2919x; 1.2919x over previous
//
#include <hip/hip_runtime.h>
#include <math.h>

#define NN 8192
#define KDIM 256
#define DD 64
#define NB 4096
#define NBLK 256
#define NTHR 512
#define RPB 32           // rows per block
#define CH 32            // sorted elements per chunk
#define NCH 256          // chunks
#define LRALPHA 0.2f

__device__ __forceinline__ unsigned f2k(float f) {
    unsigned u = __float_as_uint(f);
    return u ^ ((u >> 31) ? 0xFFFFFFFFu : 0x80000000u);
}
__device__ __forceinline__ float k2f(unsigned k) {
    return __uint_as_float((k & 0x80000000u) ? (k ^ 0x80000000u) : ~k);
}
// monotone non-decreasing key->bucket map (same formula everywhere)
__device__ __forceinline__ unsigned bucket_of(unsigned key, unsigned kmin, float scale) {
    unsigned d = key - kmin;
    unsigned b = (unsigned)((float)d * scale);
    return b > (NB - 1) ? (NB - 1) : b;
}

// Flag-array grid barrier. Arrival: one RELAXED store per block (own word, no RMW).
// Block 0 polls all flags with RELAXED loads (no per-poll cache invalidate), then
// stores a release word. Everyone fences ONCE after exit. Co-residency guaranteed:
// 256 blocks / 256 CUs, 8 waves + 21KB LDS + 64 VGPR per block.
__device__ __forceinline__ void gridbar(volatile unsigned* flags, volatile unsigned* rel, unsigned phase) {
    __syncthreads();
    __threadfence();   // release: make this block's prior writes visible
    const int t = threadIdx.x;
    const int bid = blockIdx.x;
    if (t == 0)
        __hip_atomic_store((unsigned*)&flags[bid], phase, __ATOMIC_RELAXED, __HIP_MEMORY_SCOPE_AGENT);
    if (bid == 0) {
        if (t < NBLK) {
            while (__hip_atomic_load((unsigned*)&flags[t], __ATOMIC_RELAXED, __HIP_MEMORY_SCOPE_AGENT) < phase)
                __builtin_amdgcn_s_sleep(8);
        }
        __syncthreads();
        if (t == 0)
            __hip_atomic_store((unsigned*)rel, phase, __ATOMIC_RELAXED, __HIP_MEMORY_SCOPE_AGENT);
    } else {
        if (t == 0) {
            while (__hip_atomic_load((unsigned*)rel, __ATOMIC_RELAXED, __HIP_MEMORY_SCOPE_AGENT) < phase)
                __builtin_amdgcn_s_sleep(8);
        }
    }
    __syncthreads();
    __threadfence();   // acquire: invalidate stale cached data ONCE
}

__global__ __launch_bounds__(NTHR, 2) void k_fused(
    const float* __restrict__ h, const float* __restrict__ W,
    const float* __restrict__ a, float* __restrict__ out,
    float* Wh, float* Wh2g, float* sv, float* wnv, float* wpv,
    float* cs_neg, float* cs_pos, float* cs_sn, float* cs_sp,
    float* PN, float* SP, float* PNs, float* SPs,
    int* sidx, int* histcur, unsigned* flags, unsigned* rel)
{
    __shared__ int      ls_bstart[NB + 1];     // 16.4 KB (hist -> scanned in place, persists to S5)
    __shared__ float    ls_wh1[RPB];
    __shared__ float    ls_wh2[RPB];
    __shared__ unsigned ls_ra[8], ls_rb[8];
    __shared__ int      ls_wsum[8];
    __shared__ float    ls_cs[8][2 * DD];      // 4 KB scratch (S3 / S4)
    __shared__ float    ls_css[16];
    __shared__ float    ls_M2, ls_scale;
    __shared__ unsigned ls_kmin;

    const int t = threadIdx.x, bid = blockIdx.x;
    const int wv = t >> 6, lane = t & 63;
    const int rowBase = bid * RPB;

    // ================= S0: GEMM (4 rows per wave) =================
    {
        const int r0 = rowBase + wv * 4;
        float acc0 = 0.f, acc1 = 0.f, acc2 = 0.f, acc3 = 0.f;
        #pragma unroll 2
        for (int k4 = 0; k4 < KDIM / 4; ++k4) {
            float w0 = W[(4 * k4 + 0) * DD + lane];
            float w1 = W[(4 * k4 + 1) * DD + lane];
            float w2 = W[(4 * k4 + 2) * DD + lane];
            float w3 = W[(4 * k4 + 3) * DD + lane];
            float4 h0 = *(const float4*)(h + (size_t)(r0 + 0) * KDIM + 4 * k4);
            float4 h1 = *(const float4*)(h + (size_t)(r0 + 1) * KDIM + 4 * k4);
            float4 h2 = *(const float4*)(h + (size_t)(r0 + 2) * KDIM + 4 * k4);
            float4 h3 = *(const float4*)(h + (size_t)(r0 + 3) * KDIM + 4 * k4);
            acc0 = fmaf(h0.x, w0, acc0); acc0 = fmaf(h0.y, w1, acc0);
            acc0 = fmaf(h0.z, w2, acc0); acc0 = fmaf(h0.w, w3, acc0);
            acc1 = fmaf(h1.x, w0, acc1); acc1 = fmaf(h1.y, w1, acc1);
            acc1 = fmaf(h1.z, w2, acc1); acc1 = fmaf(h1.w, w3, acc1);
            acc2 = fmaf(h2.x, w0, acc2); acc2 = fmaf(h2.y, w1, acc2);
            acc2 = fmaf(h2.z, w2, acc2); acc2 = fmaf(h2.w, w3, acc2);
            acc3 = fmaf(h3.x, w0, acc3); acc3 = fmaf(h3.y, w1, acc3);
            acc3 = fmaf(h3.z, w2, acc3); acc3 = fmaf(h3.w, w3, acc3);
        }
        float a1 = a[lane], a2 = a[DD + lane];
        float accs[4] = {acc0, acc1, acc2, acc3};
        #pragma unroll
        for (int i = 0; i < 4; ++i) {
            int row = r0 + i;
            Wh[(size_t)row * DD + lane] = accs[i];
            float r1 = accs[i] * a1, r2 = accs[i] * a2;
            #pragma unroll
            for (int off = 32; off > 0; off >>= 1) {
                r1 += __shfl_xor(r1, off, 64);
                r2 += __shfl_xor(r2, off, 64);
            }
            if (lane == 0) {
                Wh2g[row] = r2;
                ls_wh1[wv * 4 + i] = r1;
                ls_wh2[wv * 4 + i] = r2;
            }
        }
    }
    gridbar(flags, rel, 1);

    // ================= S1: redundant min/max + hist + scan -> LDS bstart =================
    for (int i = t; i < NB; i += NTHR) ls_bstart[i] = 0;
    {
        unsigned lmin = 0xFFFFFFFFu, lmax = 0u;
        for (int i = t; i < NN; i += NTHR) {
            unsigned k = f2k(Wh2g[i]);
            lmin = min(lmin, k); lmax = max(lmax, k);
        }
        #pragma unroll
        for (int off = 32; off > 0; off >>= 1) {
            lmin = min(lmin, (unsigned)__shfl_xor((int)lmin, off, 64));
            lmax = max(lmax, (unsigned)__shfl_xor((int)lmax, off, 64));
        }
        if (lane == 0) { ls_ra[wv] = lmin; ls_rb[wv] = lmax; }
    }
    __syncthreads();
    if (t == 0) {
        unsigned mn = ls_ra[0], mx = ls_rb[0];
        for (int i = 1; i < 8; ++i) { mn = min(mn, ls_ra[i]); mx = max(mx, ls_rb[i]); }
        ls_kmin = mn;
        ls_scale = (float)NB / ((float)(mx - mn) + 1.0f);
        ls_M2 = k2f(mx);
    }
    __syncthreads();
    const unsigned kmin = ls_kmin;
    const float scale = ls_scale;
    const float M2 = ls_M2;

    for (int i = t; i < NN; i += NTHR)
        atomicAdd(&ls_bstart[bucket_of(f2k(Wh2g[i]), kmin, scale)], 1);
    __syncthreads();
    {
        int s[8]; int tot = 0;
        #pragma unroll
        for (int j = 0; j < 8; ++j) { s[j] = ls_bstart[8 * t + j]; tot += s[j]; }
        int x = tot;
        #pragma unroll
        for (int off = 1; off < 64; off <<= 1) {
            int y = __shfl_up(x, off, 64);
            if (lane >= off) x += y;
        }
        if (lane == 63) ls_wsum[wv] = x;
        __syncthreads();
        int woff = 0;
        for (int w2 = 0; w2 < wv; ++w2) woff += ls_wsum[w2];
        int acc = woff + x - tot;
        #pragma unroll
        for (int j = 0; j < 8; ++j) { ls_bstart[8 * t + j] = acc; acc += s[j]; }
        if (t == 0) ls_bstart[NB] = NN;
    }
    __syncthreads();
    // one writer per bin range: block bid owns [16*bid, 16*bid+16)
    if (t < 16) histcur[16 * bid + t] = ls_bstart[16 * bid + t];

    gridbar(flags, rel, 2);

    // ================= S2: scatter own 32 elements =================
    if (t < RPB) {
        float x = ls_wh2[t];
        unsigned b = bucket_of(f2k(x), kmin, scale);
        int pos = atomicAdd(&histcur[b], 1);
        sv[pos] = x;
        sidx[pos] = rowBase + t;
        wnv[pos] = expf(LRALPHA * (x - M2));   // <= 1
        wpv[pos] = expf(x - M2);               // <= 1
    }
    gridbar(flags, rel, 3);

    // ================= S3: chunk sums (chunk = bid) =================
    {
        int base = bid * CH + wv * 4;
        float an = 0.f, ap = 0.f, sn = 0.f, sp = 0.f;
        #pragma unroll
        for (int kk = 0; kk < 4; ++kk) {
            int k = base + kk;
            int j = sidx[k];
            float g = Wh[(size_t)j * DD + lane];
            float wnk = wnv[k], wpk = wpv[k];
            an = fmaf(wnk, g, an); ap = fmaf(wpk, g, ap);
            sn += wnk; sp += wpk;
        }
        ls_cs[wv][lane] = an; ls_cs[wv][DD + lane] = ap;
        if (lane == 0) { ls_css[wv] = sn; ls_css[8 + wv] = sp; }
        __syncthreads();
        if (wv == 0) {
            float s = 0.f;
            #pragma unroll
            for (int w2 = 0; w2 < 8; ++w2) s += ls_cs[w2][lane];
            cs_neg[bid * DD + lane] = s;
            if (lane == 0) { float ss = 0.f; for (int w2 = 0; w2 < 8; ++w2) ss += ls_css[w2]; cs_sn[bid] = ss; }
        } else if (wv == 1) {
            float s = 0.f;
            #pragma unroll
            for (int w2 = 0; w2 < 8; ++w2) s += ls_cs[w2][DD + lane];
            cs_pos[bid * DD + lane] = s;
            if (lane == 0) { float ss = 0.f; for (int w2 = 0; w2 < 8; ++w2) ss += ls_css[8 + w2]; cs_sp[bid] = ss; }
        }
    }
    gridbar(flags, rel, 4);

    // ================= S4: block 0 scans the 256 chunks =================
    if (bid == 0) {
        const int c0 = wv * 32;
        float ln = 0.f, lp = 0.f, lsn = 0.f, lsp = 0.f;
        for (int c = c0; c < c0 + 32; ++c) {
            ln += cs_neg[c * DD + lane];
            lp += cs_pos[c * DD + lane];
            lsn += cs_sn[c];
            lsp += cs_sp[c];
        }
        ls_cs[wv][lane] = ln; ls_cs[wv][DD + lane] = lp;
        if (lane == 0) { ls_css[wv] = lsn; ls_css[8 + wv] = lsp; }
        __syncthreads();
        float offN = 0.f, offP = 0.f, offNs = 0.f, offPs = 0.f;
        for (int w2 = 0; w2 < wv; ++w2) { offN += ls_cs[w2][lane]; offNs += ls_css[w2]; }
        for (int w2 = wv + 1; w2 < 8; ++w2) { offP += ls_cs[w2][DD + lane]; offPs += ls_css[8 + w2]; }
        float accn = offN, accns = offNs;
        for (int c = c0; c < c0 + 32; ++c) {
            PN[c * DD + lane] = accn;
            if (lane == 0) PNs[c] = accns;
            accn += cs_neg[c * DD + lane];
            accns += cs_sn[c];
        }
        if (wv == 7) {
            PN[NCH * DD + lane] = accn;
            SP[NCH * DD + lane] = 0.f;
            if (lane == 0) { PNs[NCH] = accns; SPs[NCH] = 0.f; }
        }
        float accp = offP, accps = offPs;
        for (int c = c0 + 31; c >= c0; --c) {
            accp += cs_pos[c * DD + lane];
            accps += cs_sp[c];
            SP[c * DD + lane] = accp;
            if (lane == 0) SPs[c] = accps;
        }
    }
    gridbar(flags, rel, 5);

    // ================= S5: output (4 rows per wave) =================
    for (int i = 0; i < 4; ++i) {
        int lr = wv * 4 + i;
        int row = rowBase + lr;
        float w1 = ls_wh1[lr];
        float z = w1 + M2;                          // max_j (Wh1_i + Wh2_j)
        float m = (z >= 0.f) ? z : LRALPHA * z;     // lrelu(z) = exact row max
        float c1 = expf(z - m);                     // exponent <= 0
        float c2 = expf(LRALPHA * z - m);           // exponent <= 0
        float tt = -w1;
        unsigned kt = f2k(tt);
        int p0 = 0, p1 = 0;
        if (kt >= kmin) {
            unsigned b = bucket_of(kt, kmin, scale);
            p0 = ls_bstart[b]; p1 = ls_bstart[b + 1];
        }
        int c0f = p0 >> 5;            // CH = 32
        int c1e = (p1 + 31) >> 5;
        float nn_ = PN[c0f * DD + lane], dn_ = PNs[c0f];
        float np_ = SP[c1e * DD + lane], dp_ = SPs[c1e];
        for (int k = c0f * 32; k < c1e * 32; ++k) {
            float vk = sv[k];
            int j = sidx[k];
            float g = Wh[(size_t)j * DD + lane];
            if (vk <= tt) { float wk = wnv[k]; nn_ = fmaf(wk, g, nn_); dn_ += wk; }
            else          { float wk = wpv[k]; np_ = fmaf(wk, g, np_); dp_ += wk; }
        }
        float num = c2 * nn_ + c1 * np_;
        float den = c2 * dn_ + c1 * dp_;
        float r = num / den;
        out[(size_t)row * DD + lane] = (r > 0.f) ? r : expm1f(r);   // elu
    }
}

extern "C" void kernel_launch(void* const* d_in, const int* in_sizes, int n_in,
                              void* d_out, int out_size, void* d_ws, size_t ws_size,
                              hipStream_t stream)
{
    const float* h = (const float*)d_in[0];
    // d_in[1] = adj (bool, unused by the reference computation)
    const float* W = (const float*)d_in[2];
    const float* a = (const float*)d_in[3];
    float* out = (float*)d_out;
    float* ws = (float*)d_ws;

    float* Wh     = ws;                              // NN*DD
    float* Wh2g   = Wh + (size_t)NN * DD;            // NN
    float* sv     = Wh2g + NN;                       // NN
    float* wnv    = sv + NN;                         // NN
    float* wpv    = wnv + NN;                        // NN
    float* cs_neg = wpv + NN;                        // NCH*DD
    float* cs_pos = cs_neg + NCH * DD;               // NCH*DD
    float* cs_sn  = cs_pos + NCH * DD;               // NCH
    float* cs_sp  = cs_sn + NCH;                     // NCH
    float* PN     = cs_sp + NCH;                     // (NCH+1)*DD
    float* SP     = PN + (NCH + 1) * DD;             // (NCH+1)*DD
    float* PNs    = SP + (NCH + 1) * DD;             // NCH+1
    float* SPs    = PNs + (NCH + 1);                 // NCH+1
    int*   sidx   = (int*)(SPs + (NCH + 1));         // NN
    int*   histcur= sidx + NN;                       // NB
    unsigned* flags = (unsigned*)(histcur + NB);     // NBLK
    unsigned* rel   = flags + NBLK;                  // 1 (+pad)

    hipMemsetAsync(flags, 0, (NBLK + 64) * sizeof(unsigned), stream);
    k_fused<<<NBLK, NTHR, 0, stream>>>(h, W, a, out,
        Wh, Wh2g, sv, wnv, wpv,
        cs_neg, cs_pos, cs_sn, cs_sp,
        PN, SP, PNs, SPs,
        sidx, histcur, flags, rel);
}

// Round 5
// 300.139 us; speedup vs baseline: 2.1628x; 1.6741x over previous
//
#include <hip/hip_runtime.h>
#include <math.h>

#define NN 8192
#define KDIM 256
#define DD 64
#define NB 4096
#define NBLK 256
#define NTHR 512
#define RPB 32           // rows per block
#define CH 8             // sorted elements per chunk
#define NCH 1024         // chunks
#define LRALPHA 0.2f

__device__ __forceinline__ unsigned f2k(float f) {
    unsigned u = __float_as_uint(f);
    return u ^ ((u >> 31) ? 0xFFFFFFFFu : 0x80000000u);
}
__device__ __forceinline__ float k2f(unsigned k) {
    return __uint_as_float((k & 0x80000000u) ? (k ^ 0x80000000u) : ~k);
}
__device__ __forceinline__ unsigned bucket_of(unsigned key, unsigned kmin, float scale) {
    unsigned d = key - kmin;
    unsigned b = (unsigned)((float)d * scale);
    return b > (NB - 1) ? (NB - 1) : b;
}

// ---- device-coherent (MALL-level) scalar ops: bypass non-coherent L1/L2, NO cache-wide fences ----
__device__ __forceinline__ void  cstf(float* p, float v) { __hip_atomic_store(p, v, __ATOMIC_RELAXED, __HIP_MEMORY_SCOPE_AGENT); }
__device__ __forceinline__ float cldf(const float* p)    { return __hip_atomic_load((float*)p, __ATOMIC_RELAXED, __HIP_MEMORY_SCOPE_AGENT); }
__device__ __forceinline__ void  csti(int* p, int v)     { __hip_atomic_store(p, v, __ATOMIC_RELAXED, __HIP_MEMORY_SCOPE_AGENT); }
__device__ __forceinline__ int   cldi(const int* p)      { return __hip_atomic_load((int*)p, __ATOMIC_RELAXED, __HIP_MEMORY_SCOPE_AGENT); }

// Fence-free grid barrier: data is already MALL-coherent (sc-bit ops), so we only need
// ordering (vmcnt drain, done by __syncthreads' implicit waitcnt) + flag handshake.
__device__ __forceinline__ void gridbar(unsigned* flags, unsigned* rel, unsigned phase) {
    asm volatile("s_waitcnt vmcnt(0)" ::: "memory");   // belt&braces: all my stores globally visible
    __syncthreads();
    const int t = threadIdx.x;
    if (blockIdx.x == 0) {
        if (t == 0)
            __hip_atomic_store(&flags[0], phase, __ATOMIC_RELAXED, __HIP_MEMORY_SCOPE_AGENT);
        if (t < NBLK) {
            while (__hip_atomic_load(&flags[t], __ATOMIC_RELAXED, __HIP_MEMORY_SCOPE_AGENT) < phase)
                __builtin_amdgcn_s_sleep(4);
        }
        __syncthreads();
        if (t == 0)
            __hip_atomic_store(rel, phase, __ATOMIC_RELAXED, __HIP_MEMORY_SCOPE_AGENT);
    } else {
        if (t == 0) {
            __hip_atomic_store(&flags[blockIdx.x], phase, __ATOMIC_RELAXED, __HIP_MEMORY_SCOPE_AGENT);
            while (__hip_atomic_load(rel, __ATOMIC_RELAXED, __HIP_MEMORY_SCOPE_AGENT) < phase)
                __builtin_amdgcn_s_sleep(4);
        }
        __syncthreads();
    }
}

__global__ __launch_bounds__(NTHR, 2) void k_fused(
    const float* __restrict__ h, const float* __restrict__ W,
    const float* __restrict__ a, float* __restrict__ out,
    float* Wh, float* Wh2g, float* sv, float* wnv, float* wpv,
    float* cs_neg, float* cs_pos, float* cs_sn, float* cs_sp,
    float* PN, float* SP, float* PNs, float* SPs,
    int* sidx, int* cnt, unsigned* flags, unsigned* rel)
{
    __shared__ int      ls_bstart[NB + 1];     // 16.4 KB, persists P1 -> P4
    __shared__ float    ls_wh1[RPB];
    __shared__ float    ls_wh2[RPB];
    __shared__ unsigned ls_ra[8], ls_rb[8];
    __shared__ int      ls_wsum[8];
    __shared__ float    ls_cs[8][2 * DD];      // 4 KB (P3 scratch)
    __shared__ float    ls_css[16];
    __shared__ float    ls_M2, ls_scale;
    __shared__ unsigned ls_kmin;

    const int t = threadIdx.x, bid = blockIdx.x;
    const int wv = t >> 6, lane = t & 63;
    const int rowBase = bid * RPB;

    // ================= P0: GEMM (4 rows per wave); h/W/a read-only -> normal cached loads ======
    {
        const int r0 = rowBase + wv * 4;
        float acc0 = 0.f, acc1 = 0.f, acc2 = 0.f, acc3 = 0.f;
        #pragma unroll 2
        for (int k4 = 0; k4 < KDIM / 4; ++k4) {
            float w0 = W[(4 * k4 + 0) * DD + lane];
            float w1 = W[(4 * k4 + 1) * DD + lane];
            float w2 = W[(4 * k4 + 2) * DD + lane];
            float w3 = W[(4 * k4 + 3) * DD + lane];
            float4 h0 = *(const float4*)(h + (size_t)(r0 + 0) * KDIM + 4 * k4);
            float4 h1 = *(const float4*)(h + (size_t)(r0 + 1) * KDIM + 4 * k4);
            float4 h2 = *(const float4*)(h + (size_t)(r0 + 2) * KDIM + 4 * k4);
            float4 h3 = *(const float4*)(h + (size_t)(r0 + 3) * KDIM + 4 * k4);
            acc0 = fmaf(h0.x, w0, acc0); acc0 = fmaf(h0.y, w1, acc0);
            acc0 = fmaf(h0.z, w2, acc0); acc0 = fmaf(h0.w, w3, acc0);
            acc1 = fmaf(h1.x, w0, acc1); acc1 = fmaf(h1.y, w1, acc1);
            acc1 = fmaf(h1.z, w2, acc1); acc1 = fmaf(h1.w, w3, acc1);
            acc2 = fmaf(h2.x, w0, acc2); acc2 = fmaf(h2.y, w1, acc2);
            acc2 = fmaf(h2.z, w2, acc2); acc2 = fmaf(h2.w, w3, acc2);
            acc3 = fmaf(h3.x, w0, acc3); acc3 = fmaf(h3.y, w1, acc3);
            acc3 = fmaf(h3.z, w2, acc3); acc3 = fmaf(h3.w, w3, acc3);
        }
        float a1 = a[lane], a2 = a[DD + lane];
        float accs[4] = {acc0, acc1, acc2, acc3};
        #pragma unroll
        for (int i = 0; i < 4; ++i) {
            int row = r0 + i;
            cstf(&Wh[(size_t)row * DD + lane], accs[i]);      // coherent: read cross-block later
            float r1 = accs[i] * a1, r2 = accs[i] * a2;
            #pragma unroll
            for (int off = 32; off > 0; off >>= 1) {
                r1 += __shfl_xor(r1, off, 64);
                r2 += __shfl_xor(r2, off, 64);
            }
            if (lane == 0) {
                cstf(&Wh2g[row], r2);                          // coherent
                ls_wh1[wv * 4 + i] = r1;                       // own-block use only
                ls_wh2[wv * 4 + i] = r2;
            }
        }
    }
    gridbar(flags, rel, 1);

    // ================= P1: redundant minmax + hist + scan (LDS) + scatter own rows ============
    for (int i = t; i < NB; i += NTHR) ls_bstart[i] = 0;
    float v16[16];
    {
        unsigned lmin = 0xFFFFFFFFu, lmax = 0u;
        #pragma unroll
        for (int q = 0; q < 16; ++q) {
            float x = cldf(&Wh2g[t + q * NTHR]);
            v16[q] = x;
            unsigned k = f2k(x);
            lmin = min(lmin, k); lmax = max(lmax, k);
        }
        #pragma unroll
        for (int off = 32; off > 0; off >>= 1) {
            lmin = min(lmin, (unsigned)__shfl_xor((int)lmin, off, 64));
            lmax = max(lmax, (unsigned)__shfl_xor((int)lmax, off, 64));
        }
        if (lane == 0) { ls_ra[wv] = lmin; ls_rb[wv] = lmax; }
    }
    __syncthreads();
    if (t == 0) {
        unsigned mn = ls_ra[0], mx = ls_rb[0];
        for (int i = 1; i < 8; ++i) { mn = min(mn, ls_ra[i]); mx = max(mx, ls_rb[i]); }
        ls_kmin = mn;
        ls_scale = (float)NB / ((float)(mx - mn) + 1.0f);
        ls_M2 = k2f(mx);
    }
    __syncthreads();
    const unsigned kmin = ls_kmin;
    const float scale = ls_scale;
    const float M2 = ls_M2;

    #pragma unroll
    for (int q = 0; q < 16; ++q)
        atomicAdd(&ls_bstart[bucket_of(f2k(v16[q]), kmin, scale)], 1);
    __syncthreads();
    {
        int s[8]; int tot = 0;
        #pragma unroll
        for (int j = 0; j < 8; ++j) { s[j] = ls_bstart[8 * t + j]; tot += s[j]; }
        int x = tot;
        #pragma unroll
        for (int off = 1; off < 64; off <<= 1) {
            int y = __shfl_up(x, off, 64);
            if (lane >= off) x += y;
        }
        if (lane == 63) ls_wsum[wv] = x;
        __syncthreads();
        int woff = 0;
        for (int w2 = 0; w2 < wv; ++w2) woff += ls_wsum[w2];
        int acc = woff + x - tot;
        #pragma unroll
        for (int j = 0; j < 8; ++j) { ls_bstart[8 * t + j] = acc; acc += s[j]; }
        if (t == 0) ls_bstart[NB] = NN;
    }
    __syncthreads();
    // scatter own 32 rows: position = identical-per-block bstart + pre-zeroed global cursor
    if (t < RPB) {
        float x = ls_wh2[t];
        unsigned b = bucket_of(f2k(x), kmin, scale);
        int pos = ls_bstart[b] + atomicAdd(&cnt[b], 1);
        cstf(&sv[pos], x);
        csti(&sidx[pos], rowBase + t);
        cstf(&wnv[pos], expf(LRALPHA * (x - M2)));   // <= 1
        cstf(&wpv[pos], expf(x - M2));               // <= 1
    }
    gridbar(flags, rel, 2);

    // ================= P2: chunk sums (waves 0-3: one CH=8 chunk each) ========================
    if (wv < 4) {
        int chk = bid * 4 + wv;
        int base = chk * CH;
        float an = 0.f, ap = 0.f, sn = 0.f, sp = 0.f;
        #pragma unroll
        for (int kk = 0; kk < CH; ++kk) {
            int k = base + kk;
            int j = cldi(&sidx[k]);
            float g = cldf(&Wh[(size_t)j * DD + lane]);
            float wnk = cldf(&wnv[k]), wpk = cldf(&wpv[k]);
            an = fmaf(wnk, g, an); ap = fmaf(wpk, g, ap);
            sn += wnk; sp += wpk;
        }
        cstf(&cs_neg[chk * DD + lane], an);
        cstf(&cs_pos[chk * DD + lane], ap);
        if (lane == 0) { cstf(&cs_sn[chk], sn); cstf(&cs_sp[chk], sp); }
    }
    gridbar(flags, rel, 3);

    // ================= P3: block 0 scans the 1024 chunks (8 waves x 128) ======================
    if (bid == 0) {
        const int c0 = wv * 128;
        float ln = 0.f, lp = 0.f, lsn = 0.f, lsp = 0.f;
        for (int c = c0; c < c0 + 128; ++c) {
            ln  += cldf(&cs_neg[c * DD + lane]);
            lp  += cldf(&cs_pos[c * DD + lane]);
            lsn += cldf(&cs_sn[c]);
            lsp += cldf(&cs_sp[c]);
        }
        ls_cs[wv][lane] = ln; ls_cs[wv][DD + lane] = lp;
        if (lane == 0) { ls_css[wv] = lsn; ls_css[8 + wv] = lsp; }
        __syncthreads();
        float offN = 0.f, offP = 0.f, offNs = 0.f, offPs = 0.f;
        for (int w2 = 0; w2 < wv; ++w2) { offN += ls_cs[w2][lane]; offNs += ls_css[w2]; }
        for (int w2 = wv + 1; w2 < 8; ++w2) { offP += ls_cs[w2][DD + lane]; offPs += ls_css[8 + w2]; }
        float accn = offN, accns = offNs;
        for (int c = c0; c < c0 + 128; ++c) {
            cstf(&PN[c * DD + lane], accn);
            if (lane == 0) cstf(&PNs[c], accns);
            accn += cldf(&cs_neg[c * DD + lane]);
            accns += cldf(&cs_sn[c]);
        }
        if (wv == 7) {
            cstf(&PN[NCH * DD + lane], accn);
            cstf(&SP[NCH * DD + lane], 0.f);
            if (lane == 0) { cstf(&PNs[NCH], accns); cstf(&SPs[NCH], 0.f); }
        }
        float accp = offP, accps = offPs;
        for (int c = c0 + 127; c >= c0; --c) {
            accp += cldf(&cs_pos[c * DD + lane]);
            accps += cldf(&cs_sp[c]);
            cstf(&SP[c * DD + lane], accp);
            if (lane == 0) cstf(&SPs[c], accps);
        }
    }
    gridbar(flags, rel, 4);

    // ================= P4: output (4 rows per wave) ===========================================
    for (int i = 0; i < 4; ++i) {
        int lr = wv * 4 + i;
        int row = rowBase + lr;
        float w1 = ls_wh1[lr];
        float z = w1 + M2;                          // max_j (Wh1_i + Wh2_j)
        float m = (z >= 0.f) ? z : LRALPHA * z;     // lrelu(z) = exact row max
        float c1 = expf(z - m);                     // exponent <= 0
        float c2 = expf(LRALPHA * z - m);           // exponent <= 0
        float tt = -w1;
        unsigned kt = f2k(tt);
        int p0 = 0, p1 = 0;
        if (kt >= kmin) {
            unsigned b = bucket_of(kt, kmin, scale);
            p0 = ls_bstart[b]; p1 = ls_bstart[b + 1];
        }
        int c0f = p0 >> 3;            // CH = 8
        int c1e = (p1 + 7) >> 3;
        float nn_ = cldf(&PN[c0f * DD + lane]), dn_ = cldf(&PNs[c0f]);
        float np_ = cldf(&SP[c1e * DD + lane]), dp_ = cldf(&SPs[c1e]);
        for (int k = c0f * CH; k < c1e * CH; ++k) {
            float vk = cldf(&sv[k]);
            int j = cldi(&sidx[k]);
            float g = cldf(&Wh[(size_t)j * DD + lane]);
            if (vk <= tt) { float wk = cldf(&wnv[k]); nn_ = fmaf(wk, g, nn_); dn_ += wk; }
            else          { float wk = cldf(&wpv[k]); np_ = fmaf(wk, g, np_); dp_ += wk; }
        }
        float num = c2 * nn_ + c1 * np_;
        float den = c2 * dn_ + c1 * dp_;
        float r = num / den;
        out[(size_t)row * DD + lane] = (r > 0.f) ? r : expm1f(r);   // elu
    }
}

extern "C" void kernel_launch(void* const* d_in, const int* in_sizes, int n_in,
                              void* d_out, int out_size, void* d_ws, size_t ws_size,
                              hipStream_t stream)
{
    const float* h = (const float*)d_in[0];
    // d_in[1] = adj (bool, unused by the reference computation)
    const float* W = (const float*)d_in[2];
    const float* a = (const float*)d_in[3];
    float* out = (float*)d_out;
    float* ws = (float*)d_ws;

    float* Wh     = ws;                              // NN*DD
    float* Wh2g   = Wh + (size_t)NN * DD;            // NN
    float* sv     = Wh2g + NN;                       // NN
    float* wnv    = sv + NN;                         // NN
    float* wpv    = wnv + NN;                        // NN
    float* cs_neg = wpv + NN;                        // NCH*DD
    float* cs_pos = cs_neg + NCH * DD;               // NCH*DD
    float* cs_sn  = cs_pos + NCH * DD;               // NCH
    float* cs_sp  = cs_sn + NCH;                     // NCH
    float* PN     = cs_sp + NCH;                     // (NCH+1)*DD
    float* SP     = PN + (NCH + 1) * DD;             // (NCH+1)*DD
    float* PNs    = SP + (NCH + 1) * DD;             // NCH+1
    float* SPs    = PNs + (NCH + 1);                 // NCH+1
    int*   sidx   = (int*)(SPs + (NCH + 1));         // NN
    unsigned* flags = (unsigned*)(sidx + NN);        // NBLK
    unsigned* rel   = flags + NBLK;                  // 1 (+pad to 256)
    int*   cnt    = (int*)(rel + 256);               // NB cursors (must start at 0)

    // zero flags + rel + cnt in one captured async memset
    hipMemsetAsync(flags, 0, (NBLK + 256 + NB) * sizeof(unsigned), stream);
    k_fused<<<NBLK, NTHR, 0, stream>>>(h, W, a, out,
        Wh, Wh2g, sv, wnv, wpv,
        cs_neg, cs_pos, cs_sn, cs_sp,
        PN, SP, PNs, SPs,
        sidx, cnt, flags, rel);
}

// Round 7
// 96.386 us; speedup vs baseline: 6.7347x; 3.1139x over previous
//
#include <hip/hip_runtime.h>
#include <math.h>

#define NN 8192
#define KDIM 256
#define DD 64
#define NB 4096
#define NBLK 256
#define NTHR 512
#define RPB 32           // rows per block
#define CH 32            // sorted elements per chunk (= rows per block)
#define NCH 256          // chunks
#define LRALPHA 0.2f

__device__ __forceinline__ unsigned f2k(float f) {
    unsigned u = __float_as_uint(f);
    return u ^ ((u >> 31) ? 0xFFFFFFFFu : 0x80000000u);
}
__device__ __forceinline__ float k2f(unsigned k) {
    return __uint_as_float((k & 0x80000000u) ? (k ^ 0x80000000u) : ~k);
}
__device__ __forceinline__ unsigned bucket_of(unsigned key, unsigned kmin, float scale) {
    unsigned d = key - kmin;
    unsigned b = (unsigned)((float)d * scale);
    return b > (NB - 1) ? (NB - 1) : b;
}

// MALL-coherent scalar ops (PROVEN correct in R5): relaxed agent-scope atomics lower to
// global_load/store_dword sc0 sc1 (L1/L2 bypass). They stay in program order, so
// BATCH-ISSUE (all loads before first use) makes N loads cost ~1 round trip, not N.
__device__ __forceinline__ void  cstf(float* p, float v) { __hip_atomic_store(p, v, __ATOMIC_RELAXED, __HIP_MEMORY_SCOPE_AGENT); }
__device__ __forceinline__ float cldf(const float* p)    { return __hip_atomic_load((float*)p, __ATOMIC_RELAXED, __HIP_MEMORY_SCOPE_AGENT); }

// Fence-free grid barrier (proven in R5): relaxed flag handshake, no cache-wide maintenance.
__device__ __forceinline__ void gridbar(unsigned* flags, unsigned* rel, unsigned phase) {
    asm volatile("s_waitcnt vmcnt(0)" ::: "memory");
    __syncthreads();
    const int t = threadIdx.x;
    if (blockIdx.x == 0) {
        if (t == 0)
            __hip_atomic_store(&flags[0], phase, __ATOMIC_RELAXED, __HIP_MEMORY_SCOPE_AGENT);
        if (t < NBLK) {
            while (__hip_atomic_load(&flags[t], __ATOMIC_RELAXED, __HIP_MEMORY_SCOPE_AGENT) < phase)
                __builtin_amdgcn_s_sleep(4);
        }
        __syncthreads();
        if (t == 0)
            __hip_atomic_store(rel, phase, __ATOMIC_RELAXED, __HIP_MEMORY_SCOPE_AGENT);
    } else {
        if (t == 0) {
            __hip_atomic_store(&flags[blockIdx.x], phase, __ATOMIC_RELAXED, __HIP_MEMORY_SCOPE_AGENT);
            while (__hip_atomic_load(rel, __ATOMIC_RELAXED, __HIP_MEMORY_SCOPE_AGENT) < phase)
                __builtin_amdgcn_s_sleep(4);
        }
        __syncthreads();
    }
}

__global__ __launch_bounds__(NTHR, 2) void k_fused(
    const float* __restrict__ h, const float* __restrict__ W,
    const float* __restrict__ a, float* __restrict__ out,
    float* Wh2g, float* sv, float* wnv, float* wpv, float* sg,
    float* cs_neg, float* cs_pos, float* cs_sn, float* cs_sp,
    float* PN, float* SP, float* PNs, float* SPs,
    int* cnt, unsigned* flags, unsigned* rel)
{
    __shared__ int      ls_bstart[NB + 1];     // 16.4 KB, persists P1 -> P4
    __shared__ float    ls_wh1[RPB];
    __shared__ float    ls_wh2[RPB];
    __shared__ unsigned ls_ra[8], ls_rb[8];
    __shared__ int      ls_wsum[8];
    __shared__ float    ls_cs[8][2 * DD];      // 4 KB scratch (P2/P3)
    __shared__ float    ls_css[16];
    __shared__ float    ls_M2, ls_scale;
    __shared__ unsigned ls_kmin;

    const int t = threadIdx.x, bid = blockIdx.x;
    const int wv = t >> 6, lane = t & 63;
    const int rowBase = bid * RPB;

    // ================= P0: GEMM; rows live in registers (myrow) until scatter ======
    float myrow[4];
    {
        const int r0 = rowBase + wv * 4;
        float acc0 = 0.f, acc1 = 0.f, acc2 = 0.f, acc3 = 0.f;
        #pragma unroll 2
        for (int k4 = 0; k4 < KDIM / 4; ++k4) {
            float w0 = W[(4 * k4 + 0) * DD + lane];
            float w1 = W[(4 * k4 + 1) * DD + lane];
            float w2 = W[(4 * k4 + 2) * DD + lane];
            float w3 = W[(4 * k4 + 3) * DD + lane];
            float4 h0 = *(const float4*)(h + (size_t)(r0 + 0) * KDIM + 4 * k4);
            float4 h1 = *(const float4*)(h + (size_t)(r0 + 1) * KDIM + 4 * k4);
            float4 h2 = *(const float4*)(h + (size_t)(r0 + 2) * KDIM + 4 * k4);
            float4 h3 = *(const float4*)(h + (size_t)(r0 + 3) * KDIM + 4 * k4);
            acc0 = fmaf(h0.x, w0, acc0); acc0 = fmaf(h0.y, w1, acc0);
            acc0 = fmaf(h0.z, w2, acc0); acc0 = fmaf(h0.w, w3, acc0);
            acc1 = fmaf(h1.x, w0, acc1); acc1 = fmaf(h1.y, w1, acc1);
            acc1 = fmaf(h1.z, w2, acc1); acc1 = fmaf(h1.w, w3, acc1);
            acc2 = fmaf(h2.x, w0, acc2); acc2 = fmaf(h2.y, w1, acc2);
            acc2 = fmaf(h2.z, w2, acc2); acc2 = fmaf(h2.w, w3, acc2);
            acc3 = fmaf(h3.x, w0, acc3); acc3 = fmaf(h3.y, w1, acc3);
            acc3 = fmaf(h3.z, w2, acc3); acc3 = fmaf(h3.w, w3, acc3);
        }
        myrow[0] = acc0; myrow[1] = acc1; myrow[2] = acc2; myrow[3] = acc3;
        float a1 = a[lane], a2 = a[DD + lane];
        #pragma unroll
        for (int i = 0; i < 4; ++i) {
            float r1 = myrow[i] * a1, r2 = myrow[i] * a2;
            #pragma unroll
            for (int off = 32; off > 0; off >>= 1) {
                r1 += __shfl_xor(r1, off, 64);
                r2 += __shfl_xor(r2, off, 64);
            }
            if (lane == 0) {
                cstf(&Wh2g[r0 + i], r2);
                ls_wh1[wv * 4 + i] = r1;
                ls_wh2[wv * 4 + i] = r2;
            }
        }
    }
    gridbar(flags, rel, 1);

    // ================= P1: redundant minmax+hist+scan (LDS) + scatter rows to sg ====
    for (int i = t; i < NB; i += NTHR) ls_bstart[i] = 0;
    float v16[16];
    #pragma unroll
    for (int q = 0; q < 16; ++q)                    // batch-issue 16 loads
        v16[q] = cldf(&Wh2g[t + q * NTHR]);
    {
        unsigned lmin = 0xFFFFFFFFu, lmax = 0u;
        #pragma unroll
        for (int q = 0; q < 16; ++q) {
            unsigned k = f2k(v16[q]);
            lmin = min(lmin, k); lmax = max(lmax, k);
        }
        #pragma unroll
        for (int off = 32; off > 0; off >>= 1) {
            lmin = min(lmin, (unsigned)__shfl_xor((int)lmin, off, 64));
            lmax = max(lmax, (unsigned)__shfl_xor((int)lmax, off, 64));
        }
        if (lane == 0) { ls_ra[wv] = lmin; ls_rb[wv] = lmax; }
    }
    __syncthreads();
    if (t == 0) {
        unsigned mn = ls_ra[0], mx = ls_rb[0];
        for (int i = 1; i < 8; ++i) { mn = min(mn, ls_ra[i]); mx = max(mx, ls_rb[i]); }
        ls_kmin = mn;
        ls_scale = (float)NB / ((float)(mx - mn) + 1.0f);
        ls_M2 = k2f(mx);
    }
    __syncthreads();
    const unsigned kmin = ls_kmin;
    const float scale = ls_scale;
    const float M2 = ls_M2;

    #pragma unroll
    for (int q = 0; q < 16; ++q)
        atomicAdd(&ls_bstart[bucket_of(f2k(v16[q]), kmin, scale)], 1);
    __syncthreads();
    {
        int s[8]; int tot = 0;
        #pragma unroll
        for (int j = 0; j < 8; ++j) { s[j] = ls_bstart[8 * t + j]; tot += s[j]; }
        int x = tot;
        #pragma unroll
        for (int off = 1; off < 64; off <<= 1) {
            int y = __shfl_up(x, off, 64);
            if (lane >= off) x += y;
        }
        if (lane == 63) ls_wsum[wv] = x;
        __syncthreads();
        int woff = 0;
        for (int w2 = 0; w2 < wv; ++w2) woff += ls_wsum[w2];
        int acc = woff + x - tot;
        #pragma unroll
        for (int j = 0; j < 8; ++j) { ls_bstart[8 * t + j] = acc; acc += s[j]; }
        if (t == 0) ls_bstart[NB] = NN;
    }
    __syncthreads();
    // scatter: batch the 4 cursor RMWs, then broadcast + store whole rows from registers
    {
        int pos4[4];
        if (lane == 0) {
            #pragma unroll
            for (int i = 0; i < 4; ++i) {
                unsigned b = bucket_of(f2k(ls_wh2[wv * 4 + i]), kmin, scale);
                pos4[i] = ls_bstart[b] + atomicAdd(&cnt[b], 1);
            }
        }
        #pragma unroll
        for (int i = 0; i < 4; ++i) {
            int lr = wv * 4 + i;
            float x = ls_wh2[lr];
            int pos = __shfl(pos4[i], 0, 64);
            cstf(&sg[(size_t)pos * DD + lane], myrow[i]);
            if (lane == 0) {
                cstf(&sv[pos], x);
                cstf(&wnv[pos], expf(LRALPHA * (x - M2)));   // <= 1
                cstf(&wpv[pos], expf(x - M2));               // <= 1
            }
        }
    }
    gridbar(flags, rel, 2);

    // ================= P2: chunk sums — chunk bid = sorted rows [32*bid, 32*bid+32) ==
    {
        int base = bid * CH + wv * 4;
        float g4[4], wn4[4], wp4[4];
        #pragma unroll
        for (int kk = 0; kk < 4; ++kk) {            // batch-issue 12 loads
            int k = base + kk;
            g4[kk]  = cldf(&sg[(size_t)k * DD + lane]);
            wn4[kk] = cldf(&wnv[k]);
            wp4[kk] = cldf(&wpv[k]);
        }
        float an = 0.f, ap = 0.f, sn = 0.f, sp = 0.f;
        #pragma unroll
        for (int kk = 0; kk < 4; ++kk) {
            an = fmaf(wn4[kk], g4[kk], an); ap = fmaf(wp4[kk], g4[kk], ap);
            sn += wn4[kk]; sp += wp4[kk];
        }
        ls_cs[wv][lane] = an; ls_cs[wv][DD + lane] = ap;
        if (lane == 0) { ls_css[wv] = sn; ls_css[8 + wv] = sp; }
        __syncthreads();
        if (wv == 0) {
            float s = 0.f;
            #pragma unroll
            for (int w2 = 0; w2 < 8; ++w2) s += ls_cs[w2][lane];
            cstf(&cs_neg[bid * DD + lane], s);
            if (lane == 0) { float ss = 0.f; for (int w2 = 0; w2 < 8; ++w2) ss += ls_css[w2]; cstf(&cs_sn[bid], ss); }
        } else if (wv == 1) {
            float s = 0.f;
            #pragma unroll
            for (int w2 = 0; w2 < 8; ++w2) s += ls_cs[w2][DD + lane];
            cstf(&cs_pos[bid * DD + lane], s);
            if (lane == 0) { float ss = 0.f; for (int w2 = 0; w2 < 8; ++w2) ss += ls_css[8 + w2]; cstf(&cs_sp[bid], ss); }
        }
    }
    gridbar(flags, rel, 3);

    // ================= P3: register-resident scans of the 256 chunk vectors =========
    if (bid == 0) {
        // exclusive prefix of neg-weighted chunk vectors -> PN[0..256]
        const int c0 = wv * 32;
        float v[32];
        #pragma unroll
        for (int j = 0; j < 32; ++j) v[j] = cldf(&cs_neg[(c0 + j) * DD + lane]);  // batch
        float tot = 0.f;
        #pragma unroll
        for (int j = 0; j < 32; ++j) tot += v[j];
        ls_cs[wv][lane] = tot;
        __syncthreads();
        float acc = 0.f;
        for (int w2 = 0; w2 < wv; ++w2) acc += ls_cs[w2][lane];
        #pragma unroll
        for (int j = 0; j < 32; ++j) { cstf(&PN[(c0 + j) * DD + lane], acc); acc += v[j]; }
        if (wv == 7) cstf(&PN[NCH * DD + lane], acc);
    } else if (bid == 1) {
        // inclusive suffix of pos-weighted chunk vectors -> SP[0..256]
        const int c0 = wv * 32;
        float v[32];
        #pragma unroll
        for (int j = 0; j < 32; ++j) v[j] = cldf(&cs_pos[(c0 + j) * DD + lane]);  // batch
        float tot = 0.f;
        #pragma unroll
        for (int j = 0; j < 32; ++j) tot += v[j];
        ls_cs[wv][lane] = tot;
        __syncthreads();
        float acc = 0.f;
        for (int w2 = wv + 1; w2 < 8; ++w2) acc += ls_cs[w2][lane];
        #pragma unroll
        for (int j = 31; j >= 0; --j) { acc += v[j]; cstf(&SP[(c0 + j) * DD + lane], acc); }
        if (wv == 7) cstf(&SP[NCH * DD + lane], 0.f);
    } else if (bid == 2) {
        if (wv == 0) {          // scalar prefix
            float s[4];
            #pragma unroll
            for (int j = 0; j < 4; ++j) s[j] = cldf(&cs_sn[4 * lane + j]);
            float tot = s[0] + s[1] + s[2] + s[3];
            float x = tot;
            #pragma unroll
            for (int off = 1; off < 64; off <<= 1) {
                float y = __shfl_up(x, off, 64);
                if (lane >= off) x += y;
            }
            float acc = x - tot;
            #pragma unroll
            for (int j = 0; j < 4; ++j) { cstf(&PNs[4 * lane + j], acc); acc += s[j]; }
            if (lane == 63) cstf(&PNs[NCH], acc);
        } else if (wv == 1) {   // scalar suffix
            float s[4];
            #pragma unroll
            for (int j = 0; j < 4; ++j) s[j] = cldf(&cs_sp[4 * lane + j]);
            float tot = s[0] + s[1] + s[2] + s[3];
            float x = tot;
            #pragma unroll
            for (int off = 1; off < 64; off <<= 1) {
                float y = __shfl_down(x, off, 64);
                if (lane < 64 - off) x += y;
            }
            float acc = x - tot;   // sum over lanes > lane
            #pragma unroll
            for (int j = 3; j >= 0; --j) { acc += s[j]; cstf(&SPs[4 * lane + j], acc); }
            if (lane == 63) cstf(&SPs[NCH], 0.f);
        }
    }
    gridbar(flags, rel, 4);

    // ================= P4: output (4 rows per wave), batched contiguous corrections ==
    for (int i = 0; i < 4; ++i) {
        int lr = wv * 4 + i;
        int row = rowBase + lr;
        float w1 = ls_wh1[lr];
        float z = w1 + M2;                          // max_j (Wh1_i + Wh2_j)
        float m = (z >= 0.f) ? z : LRALPHA * z;     // lrelu(z) = exact row max
        float c1 = expf(z - m);                     // exponent <= 0
        float c2 = expf(LRALPHA * z - m);           // exponent <= 0
        float tt = -w1;
        unsigned kt = f2k(tt);
        int p0 = 0, p1 = 0;
        if (kt >= kmin) {
            unsigned b = bucket_of(kt, kmin, scale);
            p0 = ls_bstart[b]; p1 = ls_bstart[b + 1];
        }
        int c0f = p0 >> 5;            // CH = 32
        int c1e = (p1 + 31) >> 5;
        float nn_ = cldf(&PN[c0f * DD + lane]), dn_ = cldf(&PNs[c0f]);
        float np_ = cldf(&SP[c1e * DD + lane]), dp_ = cldf(&SPs[c1e]);
        // window length is a multiple of 32 -> batch by 8
        for (int base2 = c0f * CH; base2 < c1e * CH; base2 += 8) {
            float sv8[8], wn8[8], wp8[8], g8[8];
            #pragma unroll
            for (int jj = 0; jj < 8; ++jj) {        // batch-issue 32 loads
                int k = base2 + jj;
                sv8[jj] = cldf(&sv[k]);
                wn8[jj] = cldf(&wnv[k]);
                wp8[jj] = cldf(&wpv[k]);
                g8[jj]  = cldf(&sg[(size_t)k * DD + lane]);
            }
            #pragma unroll
            for (int jj = 0; jj < 8; ++jj) {
                if (sv8[jj] <= tt) { nn_ = fmaf(wn8[jj], g8[jj], nn_); dn_ += wn8[jj]; }
                else               { np_ = fmaf(wp8[jj], g8[jj], np_); dp_ += wp8[jj]; }
            }
        }
        float num = c2 * nn_ + c1 * np_;
        float den = c2 * dn_ + c1 * dp_;
        float r = num / den;
        out[(size_t)row * DD + lane] = (r > 0.f) ? r : expm1f(r);   // elu
    }
}

extern "C" void kernel_launch(void* const* d_in, const int* in_sizes, int n_in,
                              void* d_out, int out_size, void* d_ws, size_t ws_size,
                              hipStream_t stream)
{
    const float* h = (const float*)d_in[0];
    // d_in[1] = adj (bool, unused by the reference computation)
    const float* W = (const float*)d_in[2];
    const float* a = (const float*)d_in[3];
    float* out = (float*)d_out;
    float* ws = (float*)d_ws;

    float* Wh2g   = ws;                              // NN
    float* sv     = Wh2g + NN;                       // NN
    float* wnv    = sv + NN;                         // NN
    float* wpv    = wnv + NN;                        // NN
    float* sg     = wpv + NN;                        // NN*DD (sorted Wh rows)
    float* cs_neg = sg + (size_t)NN * DD;            // NCH*DD
    float* cs_pos = cs_neg + NCH * DD;               // NCH*DD
    float* cs_sn  = cs_pos + NCH * DD;               // NCH
    float* cs_sp  = cs_sn + NCH;                     // NCH
    float* PN     = cs_sp + NCH;                     // (NCH+1)*DD
    float* SP     = PN + (NCH + 1) * DD;             // (NCH+1)*DD
    float* PNs    = SP + (NCH + 1) * DD;             // NCH+1 (pad 320)
    float* SPs    = PNs + 320;                       // NCH+1 (pad 320)
    unsigned* flags = (unsigned*)(SPs + 320);        // NBLK
    unsigned* rel   = flags + NBLK;                  // 1 (+pad to 256)
    int*   cnt    = (int*)(rel + 256);               // NB cursors (must start at 0)

    // zero flags + rel + cnt in one captured async memset
    hipMemsetAsync(flags, 0, (NBLK + 256 + NB) * sizeof(unsigned), stream);
    k_fused<<<NBLK, NTHR, 0, stream>>>(h, W, a, out,
        Wh2g, sv, wnv, wpv, sg,
        cs_neg, cs_pos, cs_sn, cs_sp,
        PN, SP, PNs, SPs,
        cnt, flags, rel);
}